// Round 3
// baseline (240.289 us; speedup 1.0000x reference)
//
#include <hip/hip_runtime.h>
#include <hip/hip_bf16.h>

#define B_ 256
#define D_ 2048
#define N_ 30000
#define INV_TEMP 20.0f
#define MOM 0.2f
#define EPSF 1e-12f
#define BN 48
#define KC 64
#define NT 625   // 30000 / 48
#define NK 32    // D_ / KC

typedef __attribute__((ext_vector_type(8))) short bf16x8;
typedef __attribute__((ext_vector_type(4))) float f32x4;

typedef const __attribute__((address_space(1))) void* gas_t;
typedef __attribute__((address_space(3))) void* las_t;
#define GLOAD16(g, l) __builtin_amdgcn_global_load_lds((gas_t)(g), (las_t)(l), 16, 0, 0)

__device__ __forceinline__ unsigned short f2bf(float f) {
  union { float f; unsigned int u; } v; v.f = f;
  unsigned int u = v.u;
  unsigned int r = (u + 0x7fffu + ((u >> 16) & 1u)) >> 16;
  return (unsigned short)r;
}

__device__ __forceinline__ float blockReduceSum256(float v) {
  __shared__ float red[4];
  #pragma unroll
  for (int m = 32; m >= 1; m >>= 1) v += __shfl_xor(v, m, 64);
  int lane = threadIdx.x & 63, w = threadIdx.x >> 6;
  __syncthreads();
  if (lane == 0) red[w] = v;
  __syncthreads();
  return red[0] + red[1] + red[2] + red[3];
}

// ---------------- Kernel A: normalize inputs, emit fp32 + bf16 copies -------
__global__ __launch_bounds__(256) void knorm(const float* __restrict__ in,
                                             float* __restrict__ x,
                                             unsigned short* __restrict__ xbf) {
  int b = blockIdx.x, t = threadIdx.x;
  const float* row = in + (size_t)b * D_;
  float vals[8]; float ss = 0.f;
  #pragma unroll
  for (int i = 0; i < 8; i++) { float f = row[t + i * 256]; vals[i] = f; ss += f * f; }
  float tot = blockReduceSum256(ss);
  float inv = 1.0f / (sqrtf(tot) + EPSF);
  #pragma unroll
  for (int i = 0; i < 8; i++) {
    float xv = vals[i] * inv;
    x[(size_t)b * D_ + t + i * 256] = xv;
    xbf[(size_t)b * D_ + t + i * 256] = f2bf(xv);
  }
}

// ---------------- Kernel B: 2-phase dbuf MFMA GEMM + partials + bank copy ---
// 512 threads = 8 waves; each wave owns 32 batch rows. BN=48 feature cols.
// xs: global_load_lds direct, linear LDS dest + inverse-swizzled global src.
// fs: reg-staged (fp32 copy to outF + bf16 cvt to LDS).
__global__ __launch_bounds__(512, 4) void kmain(const float* __restrict__ feats,
                                                const unsigned short* __restrict__ xbf,
                                                float* __restrict__ outF,
                                                float* __restrict__ pmax,
                                                float* __restrict__ psum) {
  __shared__ __align__(16) unsigned short xs[2][16384];  // 2 x 32 KB
  __shared__ __align__(16) unsigned short fs[2][3072];   // 2 x 6 KB
  int tid = threadIdx.x, wave = tid >> 6, lane = tid & 63;
  int n0 = blockIdx.x * BN;

  // gl_lds inverse-swizzle source: lane l writes LDS row b=wave*8+(l>>3),
  // chunk g'=l&7 linearly; content must be global chunk g = g' ^ (b&7).
  int gswz = (lane & 7) ^ (lane >> 3);
  int bbase = wave * 8 + (lane >> 3);
  const char* xsrc = (const char*)xbf;

  f32x4 acc[2][3];
  #pragma unroll
  for (int i = 0; i < 2; i++)
    #pragma unroll
    for (int j = 0; j < 3; j++) acc[i][j] = f32x4{0.f, 0.f, 0.f, 0.f};

  // feats staging assignment: fi = tid + i*512 -> row n=fi>>5, 8B chunk c=fi&31
  int fn[3], fc[3];
  #pragma unroll
  for (int i = 0; i < 3; i++) { int fi = tid + i * 512; fn[i] = fi >> 5; fc[i] = fi & 31; }
  int sl = (lane & 32) | ((lane + 1) & 31);  // next lane within 32-group (wrap)
  float2 fv[3];

  // ---- prologue: stage tile 0 into buf 0 ----
  {
    #pragma unroll
    for (int i = 0; i < 3; i++)
      fv[i] = *(const float2*)(feats + (size_t)(n0 + fn[i]) * D_ + 2 * fc[i]);
    size_t gb = ((size_t)bbase * D_ + gswz * 8) * 2;
    #pragma unroll
    for (int i = 0; i < 4; i++)
      GLOAD16(xsrc + gb + (size_t)i * 64 * D_ * 2,
              (char*)&xs[0][0] + i * 8192 + wave * 1024);
    #pragma unroll
    for (int i = 0; i < 3; i++) {
      float nx = __shfl(fv[i].x, sl, 64);
      size_t e = (size_t)(n0 + fn[i]) * D_ + 2 * fc[i];  // feature flat idx of fv[i].x
      if (fc[i] < 31) *(float2*)(outF + e + 1) = make_float2(fv[i].y, nx);
      else { outF[e + 1] = fv[i].y; outF[e - 62] = nx; }
      ushort2 p = make_ushort2(f2bf(fv[i].x), f2bf(fv[i].y));
      int byte = fn[i] * 128 + ((4 * fc[i]) ^ ((fn[i] & 7) << 4));
      *(ushort2*)((char*)&fs[0][0] + byte) = p;
    }
  }
  __syncthreads();

  int q = lane >> 4, lr = lane & 15;
  for (int t = 0; t < NK; t++) {
    int cur = t & 1, nxt = cur ^ 1;
    if (t < NK - 1) {
      int k0 = (t + 1) * KC;
      // issue feats loads FIRST (released by counted vmcnt before gl_lds drain)
      #pragma unroll
      for (int i = 0; i < 3; i++)
        fv[i] = *(const float2*)(feats + (size_t)(n0 + fn[i]) * D_ + k0 + 2 * fc[i]);
      size_t gb = ((size_t)bbase * D_ + k0 + gswz * 8) * 2;
      #pragma unroll
      for (int i = 0; i < 4; i++)
        GLOAD16(xsrc + gb + (size_t)i * 64 * D_ * 2,
                (char*)&xs[nxt][0] + i * 8192 + wave * 1024);
    }
    // ---- compute tile t from buf[cur] ----
    #pragma unroll
    for (int ks = 0; ks < 2; ks++) {
      int g = ks * 4 + q;
      bf16x8 a0, a1, b0, b1, b2;
      { int row = wave * 32 + lr;      a0 = *(const bf16x8*)((char*)&xs[cur][0] + row * 128 + ((g * 16) ^ ((row & 7) << 4))); }
      { int row = wave * 32 + 16 + lr; a1 = *(const bf16x8*)((char*)&xs[cur][0] + row * 128 + ((g * 16) ^ ((row & 7) << 4))); }
      { int row = lr;                  b0 = *(const bf16x8*)((char*)&fs[cur][0] + row * 128 + ((g * 16) ^ ((row & 7) << 4))); }
      { int row = 16 + lr;             b1 = *(const bf16x8*)((char*)&fs[cur][0] + row * 128 + ((g * 16) ^ ((row & 7) << 4))); }
      { int row = 32 + lr;             b2 = *(const bf16x8*)((char*)&fs[cur][0] + row * 128 + ((g * 16) ^ ((row & 7) << 4))); }
      acc[0][0] = __builtin_amdgcn_mfma_f32_16x16x32_bf16(a0, b0, acc[0][0], 0, 0, 0);
      acc[0][1] = __builtin_amdgcn_mfma_f32_16x16x32_bf16(a0, b1, acc[0][1], 0, 0, 0);
      acc[0][2] = __builtin_amdgcn_mfma_f32_16x16x32_bf16(a0, b2, acc[0][2], 0, 0, 0);
      acc[1][0] = __builtin_amdgcn_mfma_f32_16x16x32_bf16(a1, b0, acc[1][0], 0, 0, 0);
      acc[1][1] = __builtin_amdgcn_mfma_f32_16x16x32_bf16(a1, b1, acc[1][1], 0, 0, 0);
      acc[1][2] = __builtin_amdgcn_mfma_f32_16x16x32_bf16(a1, b2, acc[1][2], 0, 0, 0);
    }
    // ---- write-late: outF copy + fs[nxt] cvt (waits feats loads after MFMA) --
    if (t < NK - 1) {
      int k0 = (t + 1) * KC;
      #pragma unroll
      for (int i = 0; i < 3; i++) {
        float nx = __shfl(fv[i].x, sl, 64);
        size_t e = (size_t)(n0 + fn[i]) * D_ + k0 + 2 * fc[i];
        if (fc[i] < 31) *(float2*)(outF + e + 1) = make_float2(fv[i].y, nx);
        else { outF[e + 1] = fv[i].y; outF[e - 62] = nx; }
        ushort2 p = make_ushort2(f2bf(fv[i].x), f2bf(fv[i].y));
        int byte = fn[i] * 128 + ((4 * fc[i]) ^ ((fn[i] & 7) << 4));
        *(ushort2*)((char*)&fs[nxt][0] + byte) = p;
      }
    }
    __syncthreads();  // drains vmcnt(0): gl_lds landed in xs[nxt], fs[nxt] visible
  }

  // ---- epilogue: per-row partial max / sumexp over this block's 48 cols ----
  #pragma unroll
  for (int mi = 0; mi < 2; mi++) {
    #pragma unroll
    for (int r = 0; r < 4; r++) {
      float v0 = acc[mi][0][r] * INV_TEMP;
      float v1 = acc[mi][1][r] * INV_TEMP;
      float v2 = acc[mi][2][r] * INV_TEMP;
      float mx = fmaxf(fmaxf(v0, v1), v2);
      #pragma unroll
      for (int m = 8; m >= 1; m >>= 1) mx = fmaxf(mx, __shfl_xor(mx, m, 64));
      float s = __expf(v0 - mx) + __expf(v1 - mx) + __expf(v2 - mx);
      #pragma unroll
      for (int m = 8; m >= 1; m >>= 1) s += __shfl_xor(s, m, 64);
      if (lr == 0) {
        int row = wave * 32 + mi * 16 + q * 4 + r;
        pmax[(size_t)row * NT + blockIdx.x] = mx;
        psum[(size_t)row * NT + blockIdx.x] = s;
      }
    }
  }
}

// ---------------- Kernel C: exact fp32 target logits ------------------------
__global__ __launch_bounds__(256) void ktdot(const float* __restrict__ feats,
                                             const float* __restrict__ x,
                                             const int* __restrict__ tgt,
                                             float* __restrict__ tdot) {
  int b = blockIdx.x, t = threadIdx.x;
  int y = tgt[b];
  const float* fr = feats + (size_t)y * D_;
  const float* xr = x + (size_t)b * D_;
  float s = 0.f;
  #pragma unroll
  for (int i = 0; i < 8; i++) s += fr[t + i * 256] * xr[t + i * 256];
  float tot = blockReduceSum256(s);
  if (t == 0) tdot[b] = tot * INV_TEMP;
}

// ---------------- Kernel D1: per-row logsumexp combine (256 blocks) ---------
__global__ __launch_bounds__(256) void kloss1(const float* __restrict__ pmax,
                                              const float* __restrict__ psum,
                                              const float* __restrict__ tdot,
                                              float* __restrict__ lb) {
  int b = blockIdx.x, t = threadIdx.x;
  float m = -INFINITY, s = 0.f;
  for (int i = t; i < NT; i += 256) {
    float mt = pmax[(size_t)b * NT + i];
    float st = psum[(size_t)b * NT + i];
    if (mt > m) { s = s * __expf(m - mt) + st; m = mt; }
    else        { s += st * __expf(mt - m); }
  }
  #pragma unroll
  for (int w = 32; w >= 1; w >>= 1) {
    float mo = __shfl_xor(m, w, 64);
    float so = __shfl_xor(s, w, 64);
    float M = fmaxf(m, mo);
    s = s * __expf(m - M) + so * __expf(mo - M);
    m = M;
  }
  __shared__ float sm[4], ssum[4];
  int lane = t & 63, w = t >> 6;
  if (lane == 0) { sm[w] = m; ssum[w] = s; }
  __syncthreads();
  if (t == 0) {
    float M = fmaxf(fmaxf(sm[0], sm[1]), fmaxf(sm[2], sm[3]));
    float S = ssum[0] * __expf(sm[0] - M) + ssum[1] * __expf(sm[1] - M) +
              ssum[2] * __expf(sm[2] - M) + ssum[3] * __expf(sm[3] - M);
    lb[b] = M + logf(S) - tdot[b];
  }
}

// ---------------- Kernel D2: mean over batch -> loss ------------------------
__global__ __launch_bounds__(256) void kloss2(const float* __restrict__ lb,
                                              float* __restrict__ out) {
  int t = threadIdx.x;
  float tot = blockReduceSum256(lb[t]);
  if (t == 0) out[0] = tot * (1.0f / 256.0f);
}

// ---------------- Kernel E: momentum update (first-occurrence chains) -------
__global__ __launch_bounds__(256) void kupdate(const float* __restrict__ feats,
                                               const float* __restrict__ x,
                                               const int* __restrict__ tgt,
                                               float* __restrict__ outF) {
  int b = blockIdx.x, t = threadIdx.x;
  int y = tgt[b];
  for (int i = 0; i < b; i++) if (tgt[i] == y) return;  // block-uniform exit
  float f[8];
  #pragma unroll
  for (int i = 0; i < 8; i++) f[i] = feats[(size_t)y * D_ + t + i * 256];
  for (int b2 = b; b2 < B_; b2++) {
    if (tgt[b2] != y) continue;  // block-uniform
    float ss = 0.f;
    #pragma unroll
    for (int i = 0; i < 8; i++) {
      f[i] = MOM * f[i] + (1.0f - MOM) * x[(size_t)b2 * D_ + t + i * 256];
      ss += f[i] * f[i];
    }
    float tot = blockReduceSum256(ss);
    float inv = 1.0f / (sqrtf(tot) + EPSF);
    #pragma unroll
    for (int i = 0; i < 8; i++) f[i] *= inv;
  }
  #pragma unroll
  for (int i = 0; i < 8; i++) outF[(size_t)y * D_ + t + i * 256] = f[i];
}

extern "C" void kernel_launch(void* const* d_in, const int* in_sizes, int n_in,
                              void* d_out, int out_size, void* d_ws, size_t ws_size,
                              hipStream_t stream) {
  const float* inputs = (const float*)d_in[0];
  const float* feats  = (const float*)d_in[1];
  const int*   tgt    = (const int*)d_in[2];
  float* out  = (float*)d_out;
  float* outF = out + 1;  // new_features, N_ x D_, 4-byte aligned only

  char* ws = (char*)d_ws;
  float*          x    = (float*)ws;                                   // 2 MB
  unsigned short* xbf  = (unsigned short*)(ws + (size_t)B_ * D_ * 4);  // 1 MB
  float*          pmax = (float*)(ws + (size_t)B_ * D_ * 4 + (size_t)B_ * D_ * 2);
  float*          psum = pmax + (size_t)B_ * NT;
  float*          tdot = psum + (size_t)B_ * NT;
  float*          lb   = tdot + B_;

  hipLaunchKernelGGL(knorm,   dim3(B_),  dim3(256), 0, stream, inputs, x, xbf);
  hipLaunchKernelGGL(kmain,   dim3(NT),  dim3(512), 0, stream, feats, xbf, outF, pmax, psum);
  hipLaunchKernelGGL(ktdot,   dim3(B_),  dim3(256), 0, stream, feats, x, tgt, tdot);
  hipLaunchKernelGGL(kloss1,  dim3(B_),  dim3(256), 0, stream, pmax, psum, tdot, lb);
  hipLaunchKernelGGL(kloss2,  dim3(1),   dim3(256), 0, stream, lb, out);
  hipLaunchKernelGGL(kupdate, dim3(B_),  dim3(256), 0, stream, feats, x, tgt, outF);
}